// Round 13
// baseline (450.071 us; speedup 1.0000x reference)
//
#include <hip/hip_runtime.h>
#include <hip/hip_bf16.h>
#include <math.h>

#define B_ 4
#define S_ 2048
#define D_ 2048
#define NH_ 16
#define NKV_ 4
#define HD_ 128

typedef short bf16x8 __attribute__((ext_vector_type(8)));
typedef float f32x4 __attribute__((ext_vector_type(4)));
typedef unsigned u32x4 __attribute__((ext_vector_type(4)));
typedef __hip_bfloat16 bf16;

// async 16B/lane global->LDS: lds dest = uniform base + lane*16
#define ASYNC_CP16(gp, lp)                                                    \
  __builtin_amdgcn_global_load_lds(                                           \
      (const __attribute__((address_space(1))) unsigned int*)(gp),            \
      (__attribute__((address_space(3))) unsigned int*)(lp), 16, 0, 0)

// ---------------- f32 -> bf16 conversion (4 elems/thread) ----------------
__global__ __launch_bounds__(256) void cvt_kernel(const float* __restrict__ in,
                                                  bf16* __restrict__ out, int n4) {
  int i = blockIdx.x * 256 + threadIdx.x;
  if (i >= n4) return;
  float4 v = ((const float4*)in)[i];
  union { ushort4 u; bf16 h[4]; } o;
  o.h[0] = __float2bfloat16(v.x);
  o.h[1] = __float2bfloat16(v.y);
  o.h[2] = __float2bfloat16(v.z);
  o.h[3] = __float2bfloat16(v.w);
  ((ushort4*)out)[i] = o.u;
}

// fused weight conversion: wq (1M float4) | wk (256K) | wv (256K) -> concat dest
__global__ __launch_bounds__(256) void cvt_w_kernel(const float* __restrict__ wq,
                                                    const float* __restrict__ wk,
                                                    const float* __restrict__ wv,
                                                    bf16* __restrict__ out) {
  int i = blockIdx.x * 256 + threadIdx.x;   // 0..1572863
  const float4* src; int off;
  if (i < 1048576)      { src = (const float4*)wq; off = i; }
  else if (i < 1310720) { src = (const float4*)wk; off = i - 1048576; }
  else                  { src = (const float4*)wv; off = i - 1310720; }
  float4 v = src[off];
  union { ushort4 u; bf16 h[4]; } o;
  o.h[0] = __float2bfloat16(v.x);
  o.h[1] = __float2bfloat16(v.y);
  o.h[2] = __float2bfloat16(v.z);
  o.h[3] = __float2bfloat16(v.w);
  ((ushort4*)out)[i] = o.u;
}

// ---------------- fused QKV GEMM + RoPE epilogue ----------------
// (frozen control: verified 131.5us / 790 TF; structure ceiling at this tile)
__global__ __launch_bounds__(512, 2) void gemm_qkv(
    const bf16* __restrict__ A, const bf16* __restrict__ W,
    bf16* __restrict__ qr, bf16* __restrict__ kr, bf16* __restrict__ vlin,
    const float* __restrict__ cosp, const float* __restrict__ sinp,
    float qscale) {
  __shared__ __align__(16) bf16 As[3][256 * 64];   // 3 x 32 KB
  __shared__ __align__(16) bf16 Bs[3][128 * 64];   // 3 x 16 KB
  const int tid = threadIdx.x;
  const int lane = tid & 63, wave = tid >> 6;      // wave 0..7
  const int wm = (wave >> 1) * 64, wn = (wave & 1) * 64;
  const int m0 = blockIdx.x * 256;
  const int hblk = blockIdx.y;
  const int n0 = hblk * 128;
  const int quad = lane >> 4, c = lane & 15;
  const int K = 2048;
  const int T = K / 64;                            // 32 K-tiles

  f32x4 acc[4][4] = {};

  const int srow = wave * 8 + (lane >> 3);
  const int gcol = ((lane & 7) ^ ((lane >> 3) & 7)) * 8;
  const bf16* Aptr = A + (size_t)(m0 + srow) * K + gcol;
  const bf16* Bptr = W + (size_t)(n0 + srow) * K + gcol;

#define STAGE_A(kb_, buf_, i_)                                                \
  ASYNC_CP16(Aptr + (size_t)(i_) * 64 * K + (kb_),                            \
             &As[buf_][((i_) * 64 + wave * 8) * 64])
#define STAGE_B(kb_, buf_, i_)                                                \
  ASYNC_CP16(Bptr + (size_t)(i_) * 64 * K + (kb_),                            \
             &Bs[buf_][((i_) * 64 + wave * 8) * 64])

  {
#pragma unroll
    for (int i = 0; i < 4; i++) STAGE_A(0, 0, i);
#pragma unroll
    for (int i = 0; i < 2; i++) STAGE_B(0, 0, i);
#pragma unroll
    for (int i = 0; i < 4; i++) STAGE_A(64, 1, i);
#pragma unroll
    for (int i = 0; i < 2; i++) STAGE_B(64, 1, i);
    asm volatile("s_waitcnt vmcnt(6)" ::: "memory");
    __builtin_amdgcn_s_barrier();
    __builtin_amdgcn_sched_barrier(0);
  }

  int cur = 0, stg = 2;
#pragma unroll 1
  for (int t = 0; t < T; ++t) {
    const bf16* Asc = &As[cur][0];
    const bf16* Bsc = &Bs[cur][0];
    const bool st = (t + 2) < T;
    const size_t kb2 = (size_t)(t + 2) * 64;

    {
      const int slot = (quad ^ (c & 7)) * 8;
      bf16x8 af[4], bfr[4];
#pragma unroll
      for (int q4 = 0; q4 < 4; q4++) {
        af[q4]  = *(const bf16x8*)(&Asc[(wm + q4 * 16 + c) * 64 + slot]);
        bfr[q4] = *(const bf16x8*)(&Bsc[(wn + q4 * 16 + c) * 64 + slot]);
      }
      if (st) { STAGE_A(kb2, stg, 0); STAGE_A(kb2, stg, 1); STAGE_A(kb2, stg, 2); }
      __builtin_amdgcn_sched_barrier(0);
      __builtin_amdgcn_s_barrier();
      __builtin_amdgcn_s_setprio(1);
#pragma unroll
      for (int mt = 0; mt < 4; mt++)
#pragma unroll
        for (int nt = 0; nt < 4; nt++)
          acc[mt][nt] = __builtin_amdgcn_mfma_f32_16x16x32_bf16(
              af[mt], bfr[nt], acc[mt][nt], 0, 0, 0);
      __builtin_amdgcn_s_setprio(0);
      __builtin_amdgcn_s_barrier();
      __builtin_amdgcn_sched_barrier(0);
    }
    {
      const int slot = ((4 + quad) ^ (c & 7)) * 8;
      bf16x8 af[4], bfr[4];
#pragma unroll
      for (int q4 = 0; q4 < 4; q4++) {
        af[q4]  = *(const bf16x8*)(&Asc[(wm + q4 * 16 + c) * 64 + slot]);
        bfr[q4] = *(const bf16x8*)(&Bsc[(wn + q4 * 16 + c) * 64 + slot]);
      }
      if (st) { STAGE_A(kb2, stg, 3); STAGE_B(kb2, stg, 0); STAGE_B(kb2, stg, 1); }
      __builtin_amdgcn_sched_barrier(0);
      __builtin_amdgcn_s_barrier();
      __builtin_amdgcn_s_setprio(1);
#pragma unroll
      for (int mt = 0; mt < 4; mt++)
#pragma unroll
        for (int nt = 0; nt < 4; nt++)
          acc[mt][nt] = __builtin_amdgcn_mfma_f32_16x16x32_bf16(
              af[mt], bfr[nt], acc[mt][nt], 0, 0, 0);
      __builtin_amdgcn_s_setprio(0);
      if (t + 1 < T) {
        if (st) asm volatile("s_waitcnt vmcnt(6)" ::: "memory");
        else    asm volatile("s_waitcnt vmcnt(0)" ::: "memory");
      }
      __builtin_amdgcn_s_barrier();
      __builtin_amdgcn_sched_barrier(0);
    }
    cur = (cur == 2) ? 0 : cur + 1;
    stg = (stg == 2) ? 0 : stg + 1;
  }
#undef STAGE_A
#undef STAGE_B

  __syncthreads();

  if (hblk >= 20) {
    const int colb = (hblk - 20) * 128 + wn;
#pragma unroll
    for (int mt = 0; mt < 4; mt++)
#pragma unroll
      for (int reg = 0; reg < 4; reg++) {
        int m = m0 + wm + mt * 16 + quad * 4 + reg;
        bf16* row = vlin + (size_t)m * (NKV_ * HD_) + colb;
#pragma unroll
        for (int nt = 0; nt < 4; nt++)
          row[nt * 16 + c] = __float2bfloat16(acc[mt][nt][reg]);
      }
  } else {
    float* Sc = (float*)&As[0][0];
    if (wn) {
#pragma unroll
      for (int mt = 0; mt < 4; mt++)
#pragma unroll
        for (int reg = 0; reg < 4; reg++) {
          int lr = wm + mt * 16 + quad * 4 + reg;
#pragma unroll
          for (int nt = 0; nt < 4; nt++)
            Sc[lr * 64 + nt * 16 + c] = acc[mt][nt][reg];
        }
    }
    __syncthreads();
    if (!wn) {
      const float scale = (hblk < 16) ? qscale : 1.0f;
#pragma unroll
      for (int mt = 0; mt < 4; mt++)
#pragma unroll
        for (int reg = 0; reg < 4; reg++) {
          int lr = wm + mt * 16 + quad * 4 + reg;
          int m = m0 + lr;
          int b = m >> 11, s = m & 2047;
          const float* cr = cosp + s * HD_;
          const float* sn = sinp + s * HD_;
          bf16* orow = (hblk < 16)
              ? qr + ((size_t)(b * NH_ + hblk) * S_ + s) * HD_
              : kr + ((size_t)(b * NKV_ + (hblk - 16)) * S_ + s) * HD_;
#pragma unroll
          for (int nt = 0; nt < 4; nt++) {
            int d1 = nt * 16 + c, d2 = d1 + 64;
            float q1 = acc[mt][nt][reg];
            float q2 = Sc[lr * 64 + d1];
            float o1 = (q1 * cr[d1] - q2 * sn[d1]) * scale;
            float o2 = (q2 * cr[d2] + q1 * sn[d2]) * scale;
            orow[d1] = __float2bfloat16(o1);
            orow[d2] = __float2bfloat16(o2);
          }
        }
    }
  }
}

// ---------------- V transpose: vlin[B*S, 512] -> [B,NKV,HD,S] -----
__global__ __launch_bounds__(256) void v_transpose(const bf16* __restrict__ in,
                                                   int instride,
                                                   bf16* __restrict__ out) {
  __shared__ __align__(16) bf16 tile[64][HD_ + 8];
  int bidx = blockIdx.x;
  int st = bidx & 31;
  int kv = (bidx >> 5) & 3;
  int b = bidx >> 7;
  int s0 = st * 64;
  int t = threadIdx.x;
  {
    int row = t >> 2;
    int colb = (t & 3) * 32;
#pragma unroll
    for (int i = 0; i < 4; i++) {
      int col = colb + i * 8;
      *(uint4*)(&tile[row][col]) = *(const uint4*)(
          &in[(size_t)(b * S_ + s0 + row) * instride + kv * HD_ + col]);
    }
  }
  __syncthreads();
  int sl = t & 63, hb = t >> 6;
#pragma unroll
  for (int i = 0; i < 32; i++) {
    int hd = i * 4 + hb;
    out[((size_t)(b * NKV_ + kv) * HD_ + hd) * S_ + s0 + sl] = tile[sl][hd];
  }
}

// ---------------- Flash attention: 32 q-rows/wave (two 16-row groups) -----
// T14 async-STAGE split: tile t+1 is loaded global->VGPR right after the
// step barrier (issue-early), computed tile t's ~600cy of MFMA hides the
// HBM latency, then dependency-ordered ds_write_b128 lands it in the back
// buffer (write-late); the next barrier publishes. Global reads are purely
// linear; the XOR swizzle moved to the ds_write address (rule #21).
__device__ __forceinline__ void attn_step2(
    const bf16* __restrict__ Ks, const bf16* __restrict__ Vs,
    bf16* __restrict__ PsA, bf16* __restrict__ PsB,
    const bf16x8* qfA, const bf16x8* qfB, f32x4* oA, f32x4* oB,
    float& mA, float& lA, float& mB, float& lB,
    bool diagA, bool diagB, int kb, int qbA, int quad, int c) {
  f32x4 sA[4] = {}, sB[4] = {};
#pragma unroll
  for (int kt = 0; kt < 4; kt++) {
    const int slot = ((kt * 4 + quad) ^ (c & 7)) * 8;
#pragma unroll
    for (int mt = 0; mt < 4; mt++) {
      bf16x8 kf = *(const bf16x8*)(&Ks[(mt * 16 + c) * 128 + slot]);
      sA[mt] = __builtin_amdgcn_mfma_f32_16x16x32_bf16(kf, qfA[kt], sA[mt], 0, 0, 0);
      sB[mt] = __builtin_amdgcn_mfma_f32_16x16x32_bf16(kf, qfB[kt], sB[mt], 0, 0, 0);
    }
  }
  if (diagA) {
    const int qg = qbA + c;
#pragma unroll
    for (int mt = 0; mt < 4; mt++)
#pragma unroll
      for (int r = 0; r < 4; r++)
        if (kb + mt * 16 + quad * 4 + r > qg) sA[mt][r] = -INFINITY;
  }
  if (diagB) {
    const int qg = qbA + 16 + c;
#pragma unroll
    for (int mt = 0; mt < 4; mt++)
#pragma unroll
      for (int r = 0; r < 4; r++)
        if (kb + mt * 16 + quad * 4 + r > qg) sB[mt][r] = -INFINITY;
  }

#define SOFTMAX_PACK(sacc, m_i, l_i, o, Psw)                                  \
  do {                                                                        \
    f32x4 mx4 = __builtin_elementwise_max(                                    \
        __builtin_elementwise_max(sacc[0], sacc[1]),                          \
        __builtin_elementwise_max(sacc[2], sacc[3]));                         \
    float mx = fmaxf(fmaxf(mx4[0], mx4[1]), fmaxf(mx4[2], mx4[3]));          \
    mx = fmaxf(mx, __shfl_xor(mx, 16, 64));                                   \
    mx = fmaxf(mx, __shfl_xor(mx, 32, 64));                                   \
    if (!__all(mx - m_i <= 8.0f)) {                                           \
      const float mnew = fmaxf(m_i, mx);                                      \
      const float alpha = exp2f(m_i - mnew);                                  \
      m_i = mnew;                                                             \
      l_i *= alpha;                                                           \
      f32x4 av;                                                               \
      av[0] = __shfl(alpha, quad * 4 + 0, 64);                                \
      av[1] = __shfl(alpha, quad * 4 + 1, 64);                                \
      av[2] = __shfl(alpha, quad * 4 + 2, 64);                                \
      av[3] = __shfl(alpha, quad * 4 + 3, 64);                                \
      _Pragma("unroll")                                                       \
      for (int nt = 0; nt < 8; nt++) o[nt] *= av;                             \
    }                                                                         \
    const f32x4 mn4 = {m_i, m_i, m_i, m_i};                                   \
    f32x4 rs4 = {0.f, 0.f, 0.f, 0.f};                                         \
    _Pragma("unroll")                                                         \
    for (int mt = 0; mt < 4; mt++) {                                          \
      f32x4 e = sacc[mt] - mn4;                                               \
      f32x4 p;                                                                \
      p[0] = exp2f(e[0]); p[1] = exp2f(e[1]);                                 \
      p[2] = exp2f(e[2]); p[3] = exp2f(e[3]);                                 \
      rs4 += p;                                                               \
      u32x4 u = __builtin_bit_cast(u32x4, p) + 0x8000u;                       \
      uint2 pk;                                                               \
      pk.x = __builtin_amdgcn_perm(u[1], u[0], 0x07060302u);                  \
      pk.y = __builtin_amdgcn_perm(u[3], u[2], 0x07060302u);                  \
      const int pslot = mt * 2 + (quad >> 1);                                 \
      *(uint2*)(&Psw[c * 64 + ((pslot ^ (c & 7)) << 3) + (quad & 1) * 4]) = pk; \
    }                                                                         \
    float rs = (rs4[0] + rs4[1]) + (rs4[2] + rs4[3]);                         \
    rs += __shfl_xor(rs, 16, 64);                                             \
    rs += __shfl_xor(rs, 32, 64);                                             \
    l_i += rs;                                                                \
  } while (0)

  SOFTMAX_PACK(sA, mA, lA, oA, PsA);
  SOFTMAX_PACK(sB, mB, lB, oB, PsB);
#undef SOFTMAX_PACK

#pragma unroll
  for (int kk = 0; kk < 2; kk++) {
    const int psl = (((kk * 4 + quad) ^ (c & 7)) << 3);
    bf16x8 pfA = *(const bf16x8*)(&PsA[c * 64 + psl]);
    bf16x8 pfB = *(const bf16x8*)(&PsB[c * 64 + psl]);
    const int slot = ((kk * 4 + quad) ^ (c & 7)) * 8;
#pragma unroll
    for (int nt = 0; nt < 8; nt++) {
      bf16x8 vf = *(const bf16x8*)(&Vs[(nt * 16 + c) * 64 + slot]);
      oA[nt] = __builtin_amdgcn_mfma_f32_16x16x32_bf16(pfA, vf, oA[nt], 0, 0, 0);
      oB[nt] = __builtin_amdgcn_mfma_f32_16x16x32_bf16(pfB, vf, oB[nt], 0, 0, 0);
    }
  }
}

// 4 waves/block, QBLK=128 (32 q-rows/wave), KVBLK=64, reg-staged dbuf K/V
// (T14), paired q-tiles (j then 15-j) -> uniform 36 steps/block. LDS 80 KB
// -> 2 blocks/CU; grid 8x64 = 512 blocks co-resident, no tail.
__global__ __launch_bounds__(256, 2) void attn_kernel(const bf16* __restrict__ Q,
                                                      const bf16* __restrict__ Kr,
                                                      const bf16* __restrict__ Vt,
                                                      float* __restrict__ O) {
  __shared__ __align__(16) bf16 Ks[2][64 * 128];    // 32 KB
  __shared__ __align__(16) bf16 Vs[2][128 * 64];    // 32 KB
  __shared__ __align__(16) bf16 Ps[4][2][16 * 64];  // 16 KB (A/B per wave)

  const int tid = threadIdx.x, lane = tid & 63, wave = tid >> 6;  // 0..3
  const int quad = lane >> 4, c = lane & 15;
  const int j = blockIdx.x;                 // pair index 0..7
  const int bh = blockIdx.y;
  const int b = bh >> 4, h = bh & 15, kv = h >> 2;
  bf16* PsA = &Ps[wave][0][0];
  bf16* PsB = &Ps[wave][1][0];

  const bf16* kbase = Kr + (size_t)(b * NKV_ + kv) * S_ * HD_;
  const bf16* vbase = Vt + (size_t)(b * NKV_ + kv) * HD_ * S_;

  // reg-staging layout: K tile 64x128 = 1024 16B-chunks; V tile 128x64 same.
  // thread covers 4 chunks of each; global linear, ds_write swizzled.
  int kgo[4], klo[4], vgo[4], vlo[4];
#pragma unroll
  for (int i = 0; i < 4; i++) {
    int kc = i * 256 + tid;                 // K chunk id
    int krow = kc >> 4, kch = kc & 15;      // 16 chunks per 128-col row
    kgo[i] = krow * HD_ + kch * 8;
    klo[i] = krow * 128 + ((kch ^ (krow & 7)) * 8);
    int vc = i * 256 + tid;                 // V chunk id
    int vrow = vc >> 3, vch = vc & 7;       // 8 chunks per 64-col row
    vgo[i] = vrow * S_ + vch * 8;
    vlo[i] = vrow * 64 + ((vch ^ (vrow & 7)) * 8);
  }

  uint4 kreg[4], vreg[4];
#define ISSUE(kb_)                                                            \
  do {                                                                        \
    _Pragma("unroll")                                                         \
    for (int i_ = 0; i_ < 4; i_++) {                                          \
      kreg[i_] = *(const uint4*)(kbase + (size_t)(kb_) * HD_ + kgo[i_]);      \
      vreg[i_] = *(const uint4*)(vbase + (kb_) + vgo[i_]);                    \
    }                                                                         \
  } while (0)
#define WRITE(buf_)                                                           \
  do {                                                                        \
    _Pragma("unroll")                                                         \
    for (int i_ = 0; i_ < 4; i_++) {                                          \
      *(uint4*)(&Ks[buf_][klo[i_]]) = kreg[i_];                               \
      *(uint4*)(&Vs[buf_][vlo[i_]]) = vreg[i_];                               \
    }                                                                         \
  } while (0)

  // two sequential passes: q-tile j then 15-j; uniform 36 tile-steps/block.
#pragma unroll 1
  for (int pass = 0; pass < 2; ++pass) {
    const int jj = pass ? (15 - j) : j;    // q-tile of 128 rows
    const int q0 = jj * 128;
    const int qb = q0 + wave * 32;         // group A rows [qb,qb+16), B +16
    const int nsteps = 2 * jj + 2;

    // issue tile-0 loads first; qf loads overlap the HBM latency
    __syncthreads();                       // prev-pass readers done
    ISSUE(0);

    bf16x8 qfA[4], qfB[4];
    {
      const bf16* qpA = Q + ((size_t)(b * NH_ + h) * S_ + qb + c) * HD_;
      const bf16* qpB = qpA + (size_t)16 * HD_;
#pragma unroll
      for (int kt = 0; kt < 4; kt++) {
        qfA[kt] = *(const bf16x8*)(qpA + kt * 32 + quad * 8);
        qfB[kt] = *(const bf16x8*)(qpB + kt * 32 + quad * 8);
      }
    }
    f32x4 oA[8] = {}, oB[8] = {};
    float mA = -INFINITY, lA = 0.f, mB = -INFINITY, lB = 0.f;

    WRITE(0);                              // dep-ordered on kreg/vreg
    int cur = 0;

#pragma unroll 1
    for (int it = 0; it < nsteps; ++it) {
      const int kb = it * 64;
      // publish buf[cur] (prev step's / prologue's ds_writes); all waves
      // done reading buf[cur^1] -> safe to refill it this step.
      __syncthreads();
      const bool stg = (it + 1 < nsteps);
      if (stg) ISSUE((it + 1) * 64);       // issue-early: flies under compute
      __builtin_amdgcn_sched_barrier(0);   // pin issue point before MFMA
      // skip tiles fully above this wave's 32 q rows (wave-uniform)
      if (kb <= qb + 31)
        attn_step2(&Ks[cur][0], &Vs[cur][0], PsA, PsB, qfA, qfB, oA, oB,
                   mA, lA, mB, lB, kb + 63 > qb, kb + 63 > qb + 16,
                   kb, qb, quad, c);
      if (stg) WRITE(cur ^ 1);             // write-late (compiler waits vmcnt)
      cur ^= 1;
    }

    // epilogue (both groups)
    float* obase = O + (size_t)b * S_ * D_ + (size_t)h * HD_;
    {
      float inv[4];
#pragma unroll
      for (int r = 0; r < 4; r++) inv[r] = 1.0f / __shfl(lA, quad * 4 + r, 64);
#pragma unroll
      for (int nt = 0; nt < 8; nt++)
#pragma unroll
        for (int r = 0; r < 4; r++)
          obase[(size_t)(qb + quad * 4 + r) * D_ + nt * 16 + c] = oA[nt][r] * inv[r];
    }
    {
      float inv[4];
#pragma unroll
      for (int r = 0; r < 4; r++) inv[r] = 1.0f / __shfl(lB, quad * 4 + r, 64);
#pragma unroll
      for (int nt = 0; nt < 8; nt++)
#pragma unroll
        for (int r = 0; r < 4; r++)
          obase[(size_t)(qb + 16 + quad * 4 + r) * D_ + nt * 16 + c] = oB[nt][r] * inv[r];
    }
  }
#undef ISSUE
#undef WRITE
}

// ---------------- host launch ----------------
extern "C" void kernel_launch(void* const* d_in, const int* in_sizes, int n_in,
                              void* d_out, int out_size, void* d_ws, size_t ws_size,
                              hipStream_t stream) {
  const float* x    = (const float*)d_in[0];
  const float* cosp = (const float*)d_in[1];
  const float* sinp = (const float*)d_in[2];
  const float* wq   = (const float*)d_in[3];
  const float* wk   = (const float*)d_in[4];
  const float* wv   = (const float*)d_in[5];
  float* out = (float*)d_out;

  char* ws = (char*)d_ws;
  const size_t MB = 1024 * 1024;
  bf16* xb    = (bf16*)(ws + 0);         // 32MB
  bf16* wqkvb = (bf16*)(ws + 32 * MB);   // 12MB: [3072, 2048] concat
  bf16* qr    = (bf16*)(ws + 44 * MB);   // 32MB
  bf16* kr    = (bf16*)(ws + 76 * MB);   // 8MB
  bf16* vlin  = (bf16*)(ws + 84 * MB);   // 8MB
  bf16* vt    = (bf16*)(ws + 92 * MB);   // 8MB

  cvt_kernel<<<16384, 256, 0, stream>>>(x, xb, 4194304);
  cvt_w_kernel<<<6144, 256, 0, stream>>>(wq, wk, wv, wqkvb);

  const float qscale = 1.4426950408889634f / 11.313708498984761f;
  gemm_qkv<<<dim3(32, 24), 512, 0, stream>>>(xb, wqkvb, qr, kr, vlin,
                                             cosp, sinp, qscale);

  v_transpose<<<512, 256, 0, stream>>>(vlin, NKV_ * HD_, vt);

  attn_kernel<<<dim3(8, 64), 256, 0, stream>>>(qr, kr, vt, out);
}